// Round 1
// baseline (129.551 us; speedup 1.0000x reference)
//
#include <hip/hip_runtime.h>
#include <math.h>

typedef __attribute__((ext_vector_type(4))) float f32x4;
typedef __attribute__((ext_vector_type(8))) short bf16x8;
typedef __attribute__((ext_vector_type(4))) short short4v;

#define TINV   10.0f      // 1/T
#define NCLS   1000
#define NCLSP  1024       // padded classes
#define DDIM   128
#define NB     65536

__device__ inline short f2bf(float f) {
  union { float f; unsigned u; } x; x.f = f;
  unsigned r = (x.u + 0x7fffu + ((x.u >> 16) & 1u)) >> 16;  // RNE
  return (short)r;
}

// mu (f32, 1000x128) -> bf16 bits, padded to 1024x128 with zeros
__global__ __launch_bounds__(256) void prep_mu(const float* __restrict__ mu,
                                               short* __restrict__ mub) {
  int idx = blockIdx.x * 256 + threadIdx.x;  // 512 blocks * 256 = 131072
  float v = 0.0f;
  if (idx < NCLS * DDIM) v = mu[idx];
  mub[idx] = (idx < NCLS * DDIM) ? f2bf(v) : (short)0;
}

// MODE 0: compactness rows = z (f32, convert on the fly), accumulate sum(pos - lse)
// MODE 1: dispersion  rows = mub (bf16), diag masked, accumulate sum(lse)
template <int MODE>
__global__ __launch_bounds__(256) void cider_lse(
    const float* __restrict__ z, const short* __restrict__ mub,
    const int* __restrict__ tgt, float* __restrict__ accum) {
  const int tid = threadIdx.x;
  const int wid = tid >> 6;
  const int lane = tid & 63;
  const int lo = lane & 15;
  const int hi = lane >> 4;
  const int bm0 = blockIdx.x * 64;

  // +8 shorts pad: 272B row stride -> banks rotate by 4 per row -> 2-way max (free)
  __shared__ short At[64][136];
  __shared__ short Bt[64][136];

  // ---- stage A tile (64 rows x 128) ----
  if (MODE == 0) {
    for (int i = tid; i < 2048; i += 256) {  // 2048 float4
      int row = i >> 5, k4 = i & 31;
      float4 v = reinterpret_cast<const float4*>(z)[(size_t)(bm0 + row) * 32 + k4];
      short4v s;
      s.x = f2bf(v.x); s.y = f2bf(v.y); s.z = f2bf(v.z); s.w = f2bf(v.w);
      *reinterpret_cast<short4v*>(&At[row][k4 * 4]) = s;
    }
  } else {
    for (int i = tid; i < 1024; i += 256) {  // 1024 x short8
      int row = i >> 4, c8 = i & 15;
      *reinterpret_cast<bf16x8*>(&At[row][c8 * 8]) =
          *reinterpret_cast<const bf16x8*>(&mub[(size_t)(bm0 + row) * DDIM + c8 * 8]);
    }
  }

  // per-row online-softmax state; wave owns rows [bm0 + wid*16, +16)
  float m_run[4], s_run[4], pos[4];
  int rowg[4], tgt_r[4];
#pragma unroll
  for (int r = 0; r < 4; ++r) {
    m_run[r] = -1e25f;  // finite sentinel: avoids inf-inf NaN with masked logits
    s_run[r] = 0.0f;
    pos[r] = -3.0e38f;
    rowg[r] = bm0 + wid * 16 + hi * 4 + r;
    if (MODE == 0) tgt_r[r] = tgt[rowg[r]];
  }

  for (int c0 = 0; c0 < NCLSP; c0 += 64) {
    __syncthreads();
    for (int i = tid; i < 1024; i += 256) {
      int row = i >> 4, c8 = i & 15;
      *reinterpret_cast<bf16x8*>(&Bt[row][c8 * 8]) =
          *reinterpret_cast<const bf16x8*>(&mub[(size_t)(c0 + row) * DDIM + c8 * 8]);
    }
    __syncthreads();

    f32x4 acc[4];
#pragma unroll
    for (int fj = 0; fj < 4; ++fj) acc[fj] = {0.f, 0.f, 0.f, 0.f};

#pragma unroll
    for (int ks = 0; ks < 4; ++ks) {
      bf16x8 a = *reinterpret_cast<const bf16x8*>(&At[wid * 16 + lo][ks * 32 + hi * 8]);
#pragma unroll
      for (int fj = 0; fj < 4; ++fj) {
        bf16x8 b = *reinterpret_cast<const bf16x8*>(&Bt[fj * 16 + lo][ks * 32 + hi * 8]);
        acc[fj] = __builtin_amdgcn_mfma_f32_16x16x32_bf16(a, b, acc[fj], 0, 0, 0);
      }
    }

    // online LSE update: D layout col=lane&15, row=(lane>>4)*4+r
#pragma unroll
    for (int fj = 0; fj < 4; ++fj) {
      int c = c0 + fj * 16 + lo;
#pragma unroll
      for (int r = 0; r < 4; ++r) {
        float logit = acc[fj][r] * TINV;
        bool invalid = (c >= NCLS) || (MODE == 1 && c == rowg[r]);
        if (invalid) logit = -1e30f;  // exp(logit - m) == 0 since m >= -1e25
        if (MODE == 0 && c == tgt_r[r]) pos[r] = logit;
        float mn = fmaxf(m_run[r], logit);
        s_run[r] = s_run[r] * __expf(m_run[r] - mn) + __expf(logit - mn);
        m_run[r] = mn;
      }
    }
  }

  // merge across the 16 lanes (lane&15) that share each row
  float v = 0.0f;
#pragma unroll
  for (int r = 0; r < 4; ++r) {
#pragma unroll
    for (int w = 1; w < 16; w <<= 1) {
      float mo = __shfl_xor(m_run[r], w);
      float so = __shfl_xor(s_run[r], w);
      float mn = fmaxf(m_run[r], mo);
      s_run[r] = s_run[r] * __expf(m_run[r] - mn) + so * __expf(mo - mn);
      m_run[r] = mn;
      pos[r] = fmaxf(pos[r], __shfl_xor(pos[r], w));
    }
    if (lo == 0) {
      float lse = m_run[r] + logf(s_run[r]);
      if (MODE == 0) v += pos[r] - lse;
      else if (rowg[r] < NCLS) v += lse;
    }
  }
#pragma unroll
  for (int w = 1; w < 64; w <<= 1) v += __shfl_xor(v, w);
  if (lane == 0) atomicAdd(&accum[MODE], v);
}

__global__ void finalize_k(const float* __restrict__ accum, float* __restrict__ out) {
  float loss_comp = -(accum[0] / (float)NB);
  float loss_dis = logf(1.0f / (float)(NCLS - 1)) + accum[1] / (float)NCLS;
  out[0] = 1.0f * loss_dis + 2.0f * loss_comp;
}

extern "C" void kernel_launch(void* const* d_in, const int* in_sizes, int n_in,
                              void* d_out, int out_size, void* d_ws, size_t ws_size,
                              hipStream_t stream) {
  const float* z = (const float*)d_in[0];
  const int* tgt = (const int*)d_in[1];
  const float* mu = (const float*)d_in[2];
  float* out = (float*)d_out;
  float* accum = (float*)d_ws;                    // accum[0], accum[1]
  short* mub = (short*)((char*)d_ws + 256);       // 1024*128 bf16 = 256 KB

  hipMemsetAsync(d_ws, 0, 256, stream);
  prep_mu<<<dim3(512), dim3(256), 0, stream>>>(mu, mub);
  cider_lse<0><<<dim3(NB / 64), dim3(256), 0, stream>>>(z, mub, tgt, accum);
  cider_lse<1><<<dim3(NCLSP / 64), dim3(256), 0, stream>>>(nullptr, mub, nullptr, accum);
  finalize_k<<<dim3(1), dim3(1), 0, stream>>>(accum, out);
}

// Round 2
// 82.256 us; speedup vs baseline: 1.5750x; 1.5750x over previous
//
#include <hip/hip_runtime.h>
#include <math.h>

typedef __attribute__((ext_vector_type(4))) float f32x4;
typedef __attribute__((ext_vector_type(8))) short bf16x8;
typedef __attribute__((ext_vector_type(4))) int int4v;

#define NCLS  1000
#define NCLSP 1024
#define DDIM  128
#define NB    65536
#define K2    14.426950408889634f   /* (1/T) * log2(e): MFMA emits base-2 logits */
#define LN2   0.6931471805599453f

__device__ inline short f2bf(float f) {
  union { float f; unsigned u; } x; x.f = f;
  unsigned r = (x.u + 0x7fffu + ((x.u >> 16) & 1u)) >> 16;  // RNE
  return (short)r;
}
__device__ inline float bf2f(short b) {
  union { unsigned u; float f; } x; x.u = ((unsigned)(unsigned short)b) << 16;
  return x.f;
}

// mu (f32, 1000x128) -> bf16 bits, zero-padded to 1024x128
__global__ __launch_bounds__(256) void prep_mu(const float* __restrict__ mu,
                                               short* __restrict__ mub) {
  int idx = (blockIdx.x * 256 + threadIdx.x) * 8;   // 64 blocks * 256 * 8 = 131072
  bf16x8 o = {0, 0, 0, 0, 0, 0, 0, 0};
  if (idx < NCLS * DDIM) {
    float4 u0 = *reinterpret_cast<const float4*>(mu + idx);
    float4 u1 = *reinterpret_cast<const float4*>(mu + idx + 4);
    o[0] = f2bf(u0.x); o[1] = f2bf(u0.y); o[2] = f2bf(u0.z); o[3] = f2bf(u0.w);
    o[4] = f2bf(u1.x); o[5] = f2bf(u1.y); o[6] = f2bf(u1.z); o[7] = f2bf(u1.w);
  }
  *reinterpret_cast<int4v*>(mub + idx) = *reinterpret_cast<int4v*>(&o);
}

// Compactness: 512 blocks x 4 waves; wave owns 32 rows (2 row-tiles of 16).
// A (z, pre-scaled by K2) in registers; B (mub) double-buffered in LDS.
__global__ __launch_bounds__(256, 2) void cider_comp(
    const float* __restrict__ z, const short* __restrict__ mub,
    const int* __restrict__ tgt, float* __restrict__ accum) {
  const int tid = threadIdx.x;
  const int wid = tid >> 6, lane = tid & 63;
  const int lo = lane & 15, hi = lane >> 4;
  const int bm0 = blockIdx.x * 128;

  __shared__ short Bt[2][64][136];   // +8 pad: 272B stride rotates banks 4/row

  // ---- A fragments (2 row-tiles x 4 ks), scaled by K2, bf16 ----
  bf16x8 a[2][4];
  int rowA[2];
#pragma unroll
  for (int rt = 0; rt < 2; ++rt) {
    int row = bm0 + wid * 32 + rt * 16 + lo;
    rowA[rt] = row;
    const float4* zp = reinterpret_cast<const float4*>(z + (size_t)row * DDIM);
#pragma unroll
    for (int ks = 0; ks < 4; ++ks) {
      float4 u0 = zp[ks * 8 + hi * 2];
      float4 u1 = zp[ks * 8 + hi * 2 + 1];
      bf16x8 s;
      s[0] = f2bf(u0.x * K2); s[1] = f2bf(u0.y * K2);
      s[2] = f2bf(u0.z * K2); s[3] = f2bf(u0.w * K2);
      s[4] = f2bf(u1.x * K2); s[5] = f2bf(u1.y * K2);
      s[6] = f2bf(u1.z * K2); s[7] = f2bf(u1.w * K2);
      a[rt][ks] = s;
    }
  }

  // ---- pos2 = (z[row]*K2) . mu[tgt[row]]  via register dot on A-frags ----
  float pd[2];
#pragma unroll
  for (int rt = 0; rt < 2; ++rt) {
    int t = tgt[rowA[rt]];
    const bf16x8* mp = reinterpret_cast<const bf16x8*>(mub + (size_t)t * DDIM);
    float acc = 0.0f;
#pragma unroll
    for (int ks = 0; ks < 4; ++ks) {
      bf16x8 mv = mp[ks * 4 + hi];
#pragma unroll
      for (int j = 0; j < 8; ++j) acc += bf2f(a[rt][ks][j]) * bf2f(mv[j]);
    }
    acc += __shfl_xor(acc, 16);
    acc += __shfl_xor(acc, 32);
    pd[rt] = acc;   // valid on all lanes of the hi-group; row = ...+rt*16+lo
  }

  // ---- staging mapping: thread t -> row t>>2, 32-short col chunk (t&3) ----
  const int srow = tid >> 2, scol = (tid & 3) * 32;

  {  // prologue: stage chunk 0
    const short* gp = mub + (size_t)srow * DDIM + scol;
#pragma unroll
    for (int j = 0; j < 4; ++j)
      *reinterpret_cast<int4v*>(&Bt[0][srow][scol + j * 8]) =
          *reinterpret_cast<const int4v*>(gp + j * 8);
  }
  __syncthreads();

  float m2[2][4], s2[2][4];
#pragma unroll
  for (int rt = 0; rt < 2; ++rt)
#pragma unroll
    for (int r = 0; r < 4; ++r) { m2[rt][r] = -1e30f; s2[rt][r] = 0.0f; }

#pragma unroll 1
  for (int c = 0; c < 16; ++c) {
    const int p = c & 1;
    int4v pre[4];
    if (c < 15) {  // T14: issue next-chunk global loads early
      const short* gp = mub + (size_t)((c + 1) * 64 + srow) * DDIM + scol;
#pragma unroll
      for (int j = 0; j < 4; ++j)
        pre[j] = *reinterpret_cast<const int4v*>(gp + j * 8);
    }

    f32x4 acc[2][4];
#pragma unroll
    for (int rt = 0; rt < 2; ++rt)
#pragma unroll
      for (int fj = 0; fj < 4; ++fj) acc[rt][fj] = {0.f, 0.f, 0.f, 0.f};

#pragma unroll
    for (int ks = 0; ks < 4; ++ks) {
      bf16x8 b[4];
#pragma unroll
      for (int fj = 0; fj < 4; ++fj)
        b[fj] = *reinterpret_cast<const bf16x8*>(&Bt[p][fj * 16 + lo][ks * 32 + hi * 8]);
#pragma unroll
      for (int rt = 0; rt < 2; ++rt)
#pragma unroll
        for (int fj = 0; fj < 4; ++fj)
          acc[rt][fj] = __builtin_amdgcn_mfma_f32_16x16x32_bf16(a[rt][ks], b[fj],
                                                                acc[rt][fj], 0, 0, 0);
    }

    // chunk-wise deferred-max online LSE (base 2); D: col=lo, row=hi*4+r
#pragma unroll
    for (int rt = 0; rt < 2; ++rt)
#pragma unroll
      for (int r = 0; r < 4; ++r) {
        float l0 = acc[rt][0][r], l1 = acc[rt][1][r];
        float l2 = acc[rt][2][r], l3 = acc[rt][3][r];
        float cm = fmaxf(fmaxf(l0, l1), fmaxf(l2, l3));
        float mo = m2[rt][r];
        float mn = fmaxf(mo, cm);
        s2[rt][r] = s2[rt][r] * __builtin_amdgcn_exp2f(mo - mn)
                  + __builtin_amdgcn_exp2f(l0 - mn) + __builtin_amdgcn_exp2f(l1 - mn)
                  + __builtin_amdgcn_exp2f(l2 - mn) + __builtin_amdgcn_exp2f(l3 - mn);
        m2[rt][r] = mn;
      }

    if (c < 15) {  // write-late into the other buffer
#pragma unroll
      for (int j = 0; j < 4; ++j)
        *reinterpret_cast<int4v*>(&Bt[p ^ 1][srow][scol + j * 8]) = pre[j];
    }
    __syncthreads();
  }

  // ---- merge the 16 lo-lanes sharing each row, correct 24 padded cols ----
  float vsum = 0.0f;
#pragma unroll
  for (int rt = 0; rt < 2; ++rt)
#pragma unroll
    for (int r = 0; r < 4; ++r) {
      float m = m2[rt][r], s = s2[rt][r];
#pragma unroll
      for (int w = 1; w < 16; w <<= 1) {
        float mo = __shfl_xor(m, w), so = __shfl_xor(s, w);
        float mn = fmaxf(m, mo);
        s = s * __builtin_amdgcn_exp2f(m - mn) + so * __builtin_amdgcn_exp2f(mo - mn);
        m = mn;
      }
      s -= 24.0f * __builtin_amdgcn_exp2f(0.0f - m);  // padded cols: logit2 == 0
      s = fmaxf(s, 1e-30f);
      float lse2 = m + __builtin_amdgcn_logf(s);      // v_log_f32 = log2
      float posv = __shfl(pd[rt], hi * 4 + r);        // pos2 for row rt*16+hi*4+r
      if (lo == 0) vsum += posv - lse2;
    }
#pragma unroll
  for (int w = 1; w < 64; w <<= 1) vsum += __shfl_xor(vsum, w);
  if (lane == 0) atomicAdd(&accum[0], vsum);
}

// Dispersion: 64 independent 1-wave blocks, 16 rows each; B from L2, no LDS.
__global__ __launch_bounds__(64) void cider_disp(const short* __restrict__ mub,
                                                 float* __restrict__ accum) {
  const int lane = threadIdx.x;
  const int lo = lane & 15, hi = lane >> 4;
  const int bm0 = blockIdx.x * 16;

  bf16x8 a[4];
#pragma unroll
  for (int ks = 0; ks < 4; ++ks)
    a[ks] = *reinterpret_cast<const bf16x8*>(
        mub + (size_t)(bm0 + lo) * DDIM + ks * 32 + hi * 8);

  int rowg[4];
#pragma unroll
  for (int r = 0; r < 4; ++r) rowg[r] = bm0 + hi * 4 + r;

  float m2[4], s2[4];
#pragma unroll
  for (int r = 0; r < 4; ++r) { m2[r] = -1e30f; s2[r] = 0.0f; }

#pragma unroll 1
  for (int c0 = 0; c0 < NCLSP; c0 += 64) {
    f32x4 acc[4];
#pragma unroll
    for (int fj = 0; fj < 4; ++fj) acc[fj] = {0.f, 0.f, 0.f, 0.f};
#pragma unroll
    for (int ks = 0; ks < 4; ++ks) {
#pragma unroll
      for (int fj = 0; fj < 4; ++fj) {
        bf16x8 b = *reinterpret_cast<const bf16x8*>(
            mub + (size_t)(c0 + fj * 16 + lo) * DDIM + ks * 32 + hi * 8);
        acc[fj] = __builtin_amdgcn_mfma_f32_16x16x32_bf16(a[ks], b, acc[fj], 0, 0, 0);
      }
    }
#pragma unroll
    for (int r = 0; r < 4; ++r) {
      float l[4];
#pragma unroll
      for (int fj = 0; fj < 4; ++fj) {
        int c = c0 + fj * 16 + lo;
        float v = acc[fj][r] * K2;
        l[fj] = (c >= NCLS || c == rowg[r]) ? -1e30f : v;  // diag + pad mask
      }
      float cm = fmaxf(fmaxf(l[0], l[1]), fmaxf(l[2], l[3]));
      float mo = m2[r];
      float mn = fmaxf(mo, cm);
      s2[r] = s2[r] * __builtin_amdgcn_exp2f(mo - mn)
            + __builtin_amdgcn_exp2f(l[0] - mn) + __builtin_amdgcn_exp2f(l[1] - mn)
            + __builtin_amdgcn_exp2f(l[2] - mn) + __builtin_amdgcn_exp2f(l[3] - mn);
      m2[r] = mn;
    }
  }

  float vsum = 0.0f;
#pragma unroll
  for (int r = 0; r < 4; ++r) {
    float m = m2[r], s = s2[r];
#pragma unroll
    for (int w = 1; w < 16; w <<= 1) {
      float mo = __shfl_xor(m, w), so = __shfl_xor(s, w);
      float mn = fmaxf(m, mo);
      s = s * __builtin_amdgcn_exp2f(m - mn) + so * __builtin_amdgcn_exp2f(mo - mn);
      m = mn;
    }
    float lse2 = m + __builtin_amdgcn_logf(fmaxf(s, 1e-30f));
    if (lo == 0 && rowg[r] < NCLS) vsum += lse2;
  }
#pragma unroll
  for (int w = 1; w < 64; w <<= 1) vsum += __shfl_xor(vsum, w);
  if (lane == 0) atomicAdd(&accum[1], vsum);
}

__global__ void finalize_k(const float* __restrict__ accum, float* __restrict__ out) {
  float loss_comp = -(LN2 * accum[0] / (float)NB);
  float loss_dis = logf(1.0f / (float)(NCLS - 1)) + LN2 * accum[1] / (float)NCLS;
  out[0] = loss_dis + 2.0f * loss_comp;
}

extern "C" void kernel_launch(void* const* d_in, const int* in_sizes, int n_in,
                              void* d_out, int out_size, void* d_ws, size_t ws_size,
                              hipStream_t stream) {
  const float* z = (const float*)d_in[0];
  const int* tgt = (const int*)d_in[1];
  const float* mu = (const float*)d_in[2];
  float* out = (float*)d_out;
  float* accum = (float*)d_ws;
  short* mub = (short*)((char*)d_ws + 256);   // 1024*128 bf16 = 256 KB

  hipMemsetAsync(d_ws, 0, 256, stream);
  prep_mu<<<dim3(64), dim3(256), 0, stream>>>(mu, mub);
  cider_comp<<<dim3(512), dim3(256), 0, stream>>>(z, mub, tgt, accum);
  cider_disp<<<dim3(64), dim3(64), 0, stream>>>(mub, accum);
  finalize_k<<<dim3(1), dim3(1), 0, stream>>>(accum, out);
}

// Round 3
// 69.648 us; speedup vs baseline: 1.8601x; 1.1810x over previous
//
#include <hip/hip_runtime.h>
#include <math.h>

typedef __attribute__((ext_vector_type(4))) float f32x4;
typedef __attribute__((ext_vector_type(8))) short bf16x8;

#define NCLS  1000
#define DDIM  128
#define NB    65536
#define K2    14.426950408889634f   /* (1/T)*log2(e): MFMA emits base-2 logits */
#define LN2   0.6931471805599453f

__device__ inline short f2bf(float f) {
  union { float f; unsigned u; } x; x.f = f;
  unsigned r = (x.u + 0x7fffu + ((x.u >> 16) & 1u)) >> 16;  // RNE
  return (short)r;
}
__device__ inline float bf2f(short b) {
  union { unsigned u; float f; } x; x.u = ((unsigned)(unsigned short)b) << 16;
  return x.f;
}
__device__ inline void gll16(const void* g, void* l) {
  __builtin_amdgcn_global_load_lds(
      (const __attribute__((address_space(1))) unsigned int*)g,
      (__attribute__((address_space(3))) unsigned int*)l, 16, 0, 0);
}

// mu (f32 1000x128) -> bf16, zero-padded to 1024 rows, 16B-chunk-swizzled:
// phys chunk index = j ^ (row&7)  (T2 swizzle baked into global layout so
// linear global_load_lds staging yields swizzled LDS).
__global__ __launch_bounds__(256) void prep_mu(const float* __restrict__ mu,
                                               short* __restrict__ mub) {
  int idx = blockIdx.x * 256 + threadIdx.x;   // 64 blocks -> 16384 chunks
  int row = idx >> 4, j = idx & 15;
  bf16x8 o = {0, 0, 0, 0, 0, 0, 0, 0};
  if (row < NCLS) {
    const float4* p = reinterpret_cast<const float4*>(mu + (size_t)row * DDIM + j * 8);
    float4 u0 = p[0], u1 = p[1];
    o[0] = f2bf(u0.x); o[1] = f2bf(u0.y); o[2] = f2bf(u0.z); o[3] = f2bf(u0.w);
    o[4] = f2bf(u1.x); o[5] = f2bf(u1.y); o[6] = f2bf(u1.z); o[7] = f2bf(u1.w);
  }
  int js = j ^ (row & 7);
  *reinterpret_cast<bf16x8*>(mub + (size_t)row * DDIM + js * 8) = o;
}

// Compactness: 512 blocks x 4 waves; wave owns 32 rows; B dbuf in LDS via
// global_load_lds; 128-col chunks (8 iters); softmax(c-1) overlaps stage(c).
__global__ __launch_bounds__(256, 2) void cider_comp(
    const float* __restrict__ z, const short* __restrict__ mub,
    const int* __restrict__ tgt, float* __restrict__ accum) {
  const int tid = threadIdx.x;
  const int wid = tid >> 6, lane = tid & 63;
  const int lo = lane & 15, hi = lane >> 4;
  const int bm0 = blockIdx.x * 128;

  __shared__ short Bt[2][128][128];   // 64 KB, linear (swizzle is in the data)

  const char* mb = (const char*)mub;
  const int soff = wid * 8192 + lane * 16;   // wave covers 8KB of the 32KB chunk
  char* const bt0 = (char*)&Bt[0][0][0];
  char* const bt1 = (char*)&Bt[1][0][0];

  auto stage = [&](int c, char* dbase) {
    const char* src = mb + (size_t)c * 32768 + soff;
    char* dst = dbase + wid * 8192;
#pragma unroll
    for (int i = 0; i < 8; ++i) gll16(src + i * 1024, dst + i * 1024);
  };

  stage(0, bt0);   // start chunk-0 DMA before the register prologue

  // ---- A fragments (scaled by K2) + pos-dot ----
  bf16x8 a[2][4];
  float pd[2];
#pragma unroll
  for (int rt = 0; rt < 2; ++rt) {
    int row = bm0 + wid * 32 + rt * 16 + lo;
    const float4* zp = reinterpret_cast<const float4*>(z + (size_t)row * DDIM);
#pragma unroll
    for (int ks = 0; ks < 4; ++ks) {
      float4 u0 = zp[ks * 8 + hi * 2];
      float4 u1 = zp[ks * 8 + hi * 2 + 1];
      bf16x8 s;
      s[0] = f2bf(u0.x * K2); s[1] = f2bf(u0.y * K2);
      s[2] = f2bf(u0.z * K2); s[3] = f2bf(u0.w * K2);
      s[4] = f2bf(u1.x * K2); s[5] = f2bf(u1.y * K2);
      s[6] = f2bf(u1.z * K2); s[7] = f2bf(u1.w * K2);
      a[rt][ks] = s;
    }
    int t = tgt[row];
    float acc = 0.f;
#pragma unroll
    for (int ks = 0; ks < 4; ++ks) {
      int j = (ks * 4 + hi) ^ (t & 7);   // de-swizzle
      bf16x8 mv = *reinterpret_cast<const bf16x8*>(mub + (size_t)t * DDIM + j * 8);
#pragma unroll
      for (int e = 0; e < 8; ++e) acc += bf2f(a[rt][ks][e]) * bf2f(mv[e]);
    }
    acc += __shfl_xor(acc, 16);
    acc += __shfl_xor(acc, 32);
    pd[rt] = acc;
  }

  const int swz = (lo & 7) << 4;

  auto do_mfma = [&](const char* bbase, f32x4 (&acc)[2][8]) {
#pragma unroll
    for (int rt = 0; rt < 2; ++rt)
#pragma unroll
      for (int fj = 0; fj < 8; ++fj) acc[rt][fj] = f32x4{0.f, 0.f, 0.f, 0.f};
#pragma unroll
    for (int ks = 0; ks < 4; ++ks) {
      bf16x8 b[8];
#pragma unroll
      for (int fj = 0; fj < 8; ++fj) {
        int addr = (fj * 16 + lo) * 256 + ((ks * 64 + hi * 16) ^ swz);
        b[fj] = *reinterpret_cast<const bf16x8*>(bbase + addr);
      }
#pragma unroll
      for (int rt = 0; rt < 2; ++rt)
#pragma unroll
        for (int fj = 0; fj < 8; ++fj)
          acc[rt][fj] = __builtin_amdgcn_mfma_f32_16x16x32_bf16(a[rt][ks], b[fj],
                                                                acc[rt][fj], 0, 0, 0);
    }
  };

  float m2[2][4], s2[2][4];
#pragma unroll
  for (int rt = 0; rt < 2; ++rt)
#pragma unroll
    for (int r = 0; r < 4; ++r) { m2[rt][r] = -1e30f; s2[rt][r] = 0.f; }

  auto do_sm = [&](f32x4 (&acc)[2][8]) {
#pragma unroll
    for (int rt = 0; rt < 2; ++rt)
#pragma unroll
      for (int r = 0; r < 4; ++r) {
        float cm = acc[rt][0][r];
#pragma unroll
        for (int fj = 1; fj < 8; ++fj) cm = fmaxf(cm, acc[rt][fj][r]);
        float mo = m2[rt][r];
        float mn = fmaxf(mo, cm);
        float sum = s2[rt][r] * __builtin_amdgcn_exp2f(mo - mn);
#pragma unroll
        for (int fj = 0; fj < 8; ++fj)
          sum += __builtin_amdgcn_exp2f(acc[rt][fj][r] - mn);
        m2[rt][r] = mn; s2[rt][r] = sum;
      }
  };

  f32x4 acc0[2][8], acc1[2][8];   // ping-pong: all indices static (rule #20)

  __syncthreads();                // chunk 0 landed (implicit vmcnt drain)
  do_mfma(bt0, acc0);
#pragma unroll 1
  for (int c2 = 1; c2 < 7; c2 += 2) {
    stage(c2, bt1);
    do_sm(acc0);
    __syncthreads();
    do_mfma(bt1, acc1);
    stage(c2 + 1, bt0);
    do_sm(acc1);
    __syncthreads();
    do_mfma(bt0, acc0);
  }
  stage(7, bt1);
  do_sm(acc0);
  __syncthreads();
  do_mfma(bt1, acc1);
  do_sm(acc1);

  // ---- merge 16 lo-lanes per row; closed-form correction for 24 pad cols ----
  float vsum = 0.f;
#pragma unroll
  for (int rt = 0; rt < 2; ++rt)
#pragma unroll
    for (int r = 0; r < 4; ++r) {
      float m = m2[rt][r], s = s2[rt][r];
#pragma unroll
      for (int w = 1; w < 16; w <<= 1) {
        float mo = __shfl_xor(m, w), so = __shfl_xor(s, w);
        float mn = fmaxf(m, mo);
        s = s * __builtin_amdgcn_exp2f(m - mn) + so * __builtin_amdgcn_exp2f(mo - mn);
        m = mn;
      }
      s -= 24.0f * __builtin_amdgcn_exp2f(0.0f - m);  // pad cols have logit2 == 0
      s = fmaxf(s, 1e-30f);
      float lse2 = m + __builtin_amdgcn_logf(s);      // v_log_f32 = log2
      float posv = __shfl(pd[rt], hi * 4 + r);
      if (lo == 0) vsum += posv - lse2;
    }
#pragma unroll
  for (int w = 1; w < 64; w <<= 1) vsum += __shfl_xor(vsum, w);
  if (lane == 0) atomicAdd(&accum[0], vsum);
}

// Dispersion: 256 blocks x 1 wave; block = (row-tile rt, col-quarter q).
// Writes partial (m,s) per row to workspace; merged in finalize.
__global__ __launch_bounds__(64) void cider_disp(const short* __restrict__ mub,
                                                 float2* __restrict__ part) {
  const int lane = threadIdx.x;
  const int lo = lane & 15, hi = lane >> 4;
  const int rt = blockIdx.x >> 2, q = blockIdx.x & 3;
  const int arow = rt * 16 + lo;

  bf16x8 a[4];
#pragma unroll
  for (int ks = 0; ks < 4; ++ks) {
    int j = (ks * 4 + hi) ^ (arow & 7);
    bf16x8 raw = *reinterpret_cast<const bf16x8*>(mub + (size_t)arow * DDIM + j * 8);
    bf16x8 s;
#pragma unroll
    for (int e = 0; e < 8; ++e) s[e] = f2bf(bf2f(raw[e]) * K2);
    a[ks] = s;
  }

  int rowg[4];
#pragma unroll
  for (int r = 0; r < 4; ++r) rowg[r] = rt * 16 + hi * 4 + r;

  float m2[4], s2[4];
#pragma unroll
  for (int r = 0; r < 4; ++r) { m2[r] = -1e30f; s2[r] = 0.f; }

#pragma unroll 1
  for (int cc = 0; cc < 4; ++cc) {
    const int c0 = q * 256 + cc * 64;
    f32x4 acc[4];
#pragma unroll
    for (int fj = 0; fj < 4; ++fj) acc[fj] = f32x4{0.f, 0.f, 0.f, 0.f};
#pragma unroll
    for (int ks = 0; ks < 4; ++ks) {
#pragma unroll
      for (int fj = 0; fj < 4; ++fj) {
        int brow = c0 + fj * 16 + lo;
        int j = (ks * 4 + hi) ^ (brow & 7);
        bf16x8 b = *reinterpret_cast<const bf16x8*>(mub + (size_t)brow * DDIM + j * 8);
        acc[fj] = __builtin_amdgcn_mfma_f32_16x16x32_bf16(a[ks], b, acc[fj], 0, 0, 0);
      }
    }
#pragma unroll
    for (int r = 0; r < 4; ++r) {
      float l[4];
#pragma unroll
      for (int fj = 0; fj < 4; ++fj) {
        int c = c0 + fj * 16 + lo;
        l[fj] = (c >= NCLS || c == rowg[r]) ? -1e30f : acc[fj][r];
      }
      float cm = fmaxf(fmaxf(l[0], l[1]), fmaxf(l[2], l[3]));
      float mo = m2[r], mn = fmaxf(mo, cm);
      s2[r] = s2[r] * __builtin_amdgcn_exp2f(mo - mn)
            + __builtin_amdgcn_exp2f(l[0] - mn) + __builtin_amdgcn_exp2f(l[1] - mn)
            + __builtin_amdgcn_exp2f(l[2] - mn) + __builtin_amdgcn_exp2f(l[3] - mn);
      m2[r] = mn;
    }
  }

#pragma unroll
  for (int r = 0; r < 4; ++r) {
    float m = m2[r], s = s2[r];
#pragma unroll
    for (int w = 1; w < 16; w <<= 1) {
      float mo = __shfl_xor(m, w), so = __shfl_xor(s, w);
      float mn = fmaxf(m, mo);
      s = s * __builtin_amdgcn_exp2f(m - mn) + so * __builtin_amdgcn_exp2f(mo - mn);
      m = mn;
    }
    m2[r] = m; s2[r] = s;
  }
  if (lo == 0) {
#pragma unroll
    for (int r = 0; r < 4; ++r)
      part[q * 1024 + rt * 16 + hi * 4 + r] = make_float2(m2[r], s2[r]);
  }
}

// Merge disp partials + final loss. One block, 1024 threads.
__global__ __launch_bounds__(1024) void finalize_k(const float* __restrict__ accum,
                                                   const float2* __restrict__ part,
                                                   float* __restrict__ out) {
  __shared__ float red[16];
  const int row = threadIdx.x;
  float m = -1e30f, s = 0.f;
#pragma unroll
  for (int qq = 0; qq < 4; ++qq) {
    float2 p = part[qq * 1024 + row];
    float mn = fmaxf(m, p.x);
    s = s * __builtin_amdgcn_exp2f(m - mn) + p.y * __builtin_amdgcn_exp2f(p.x - mn);
    m = mn;
  }
  float v = 0.f;
  if (row < NCLS) v = m + __builtin_amdgcn_logf(fmaxf(s, 1e-30f));
#pragma unroll
  for (int w = 1; w < 64; w <<= 1) v += __shfl_xor(v, w);
  if ((row & 63) == 0) red[row >> 6] = v;
  __syncthreads();
  if (row == 0) {
    float t = 0.f;
#pragma unroll
    for (int i = 0; i < 16; ++i) t += red[i];
    float loss_comp = -(LN2 * accum[0] / (float)NB);
    float loss_dis = logf(1.0f / (float)(NCLS - 1)) + LN2 * t / (float)NCLS;
    out[0] = loss_dis + 2.0f * loss_comp;
  }
}

extern "C" void kernel_launch(void* const* d_in, const int* in_sizes, int n_in,
                              void* d_out, int out_size, void* d_ws, size_t ws_size,
                              hipStream_t stream) {
  const float* z = (const float*)d_in[0];
  const int* tgt = (const int*)d_in[1];
  const float* mu = (const float*)d_in[2];
  float* out = (float*)d_out;
  float* accum = (float*)d_ws;                               // 256 B
  short* mub = (short*)((char*)d_ws + 256);                  // 256 KB (swizzled)
  float2* part = (float2*)((char*)d_ws + 256 + 262144);      // 32 KB

  hipMemsetAsync(d_ws, 0, 256, stream);
  prep_mu<<<dim3(64), dim3(256), 0, stream>>>(mu, mub);
  cider_comp<<<dim3(512), dim3(256), 0, stream>>>(z, mub, tgt, accum);
  cider_disp<<<dim3(256), dim3(64), 0, stream>>>(mub, part);
  finalize_k<<<dim3(1), dim3(1024), 0, stream>>>(accum, part, out);
}